// Round 6
// baseline (868.853 us; speedup 1.0000x reference)
//
#include <hip/hip_runtime.h>
#include <hip/hip_bf16.h>
#include <math.h>

typedef __bf16 bf16_t;
typedef __bf16 bf16x8 __attribute__((ext_vector_type(8)));
typedef __bf16 bf16x4 __attribute__((ext_vector_type(4)));
typedef float  f32x4  __attribute__((ext_vector_type(4)));

enum { EPI_BF16_BIAS = 0, EPI_F32_SCALE = 1, EPI_BF16 = 2, EPI_F32_BIAS_RES = 3, EPI_BF16_BIAS_GELU = 4 };

__device__ __forceinline__ float gelu_exact(float v) {
  return 0.5f * v * (1.0f + erff(v * 0.7071067811865476f));
}

__device__ __forceinline__ void gld_lds16(const bf16_t* g, bf16_t* l) {
  __builtin_amdgcn_global_load_lds(
      (const __attribute__((address_space(1))) uint32_t*)(uintptr_t)g,
      (__attribute__((address_space(3))) uint32_t*)(uintptr_t)l, 16, 0, 0);
}

#define SB()    __builtin_amdgcn_s_barrier()
#define SCHED() __builtin_amdgcn_sched_barrier(0)
#define VMW8()  asm volatile("s_waitcnt vmcnt(8)" ::: "memory")
#define VMW4()  asm volatile("s_waitcnt vmcnt(4)" ::: "memory")
#define VMW0()  asm volatile("s_waitcnt vmcnt(0)" ::: "memory")

// ---------------- GEMM: 256x256 tile, BK=32 stages, 4-deep LDS pipeline, 8 waves ----
// C[M][N] = A[M][K] @ B^T (+ epilogue). A:[M][K] bf16 (lda), B:[N][K] bf16 (ldb).
// M,N multiples of 256; K multiple of 128 (NT multiple of 4, NT>=4).
// Stage body: { issue stage(t+3) [4 gload_lds]; 12x ds_read_b128; 32 MFMA;
//               counted vmcnt(8) [t+1 landed, t+2/t+3 stay in flight]; s_barrier }
// BK=32 => 64-B LDS rows: fragment reads (row=base+lr, 16B slot=lg) tile all 32
// banks natively (bank = (lr*16+lg*4)&31, 8 lanes/bank = b128 minimum) -> no swizzle.
template<int EPI>
__global__ __launch_bounds__(512, 2) void tb_gemm8(
    const bf16_t* __restrict__ A, int lda, long long strideA,
    const bf16_t* __restrict__ B, int ldb, long long strideB,
    const float* __restrict__ bias,
    const float* __restrict__ resid,
    void* __restrict__ Cp, int ldc, long long strideC,
    int K, float scale)
{
  __shared__ __align__(16) bf16_t sm[65536];  // 128 KiB: 4 bufs x (A 8192 + B 8192 elems)

  const int tid = threadIdx.x;
  const int lane = tid & 63;
  const int wid = tid >> 6;
  const int wm = wid >> 2;   // 0..1  (M wave group, 16-row interleave)
  const int wn = wid & 3;    // 0..3  (N wave group, 16-col interleave)
  const int lr = lane & 15;
  const int lg = lane >> 4;
  const int z = blockIdx.z;
  const int m0 = blockIdx.y * 256;
  const int n0 = blockIdx.x * 256;

  const bf16_t* Ag = A + (size_t)z * strideA + (size_t)m0 * lda;
  const bf16_t* Bg = B + (size_t)z * strideB + (size_t)n0 * ldb;

  const int srow = lane >> 2;        // 0..15 row within 16-row chunk
  const int scol = (lane & 3) * 8;   // 16B column within 64-B row

  f32x4 acc[8][4];
#pragma unroll
  for (int i = 0; i < 8; ++i)
#pragma unroll
    for (int j = 0; j < 4; ++j) acc[i][j] = (f32x4){0.f, 0.f, 0.f, 0.f};

  // stage one BK=32 K-slice of A and B (256 rows each) into buffer `buf`:
  // 4 gload_lds per wave (A x2, B x2). Linear LDS [row][k].
  auto stage = [&](bf16_t* buf, int kt) {
#pragma unroll
    for (int q = 0; q < 2; ++q) {
      int c = (wid << 1) + q;            // chunk 0..15 (16 rows, 1024 B each)
      int row = (c << 4) + srow;
      gld_lds16(Ag + (size_t)row * lda + kt + scol, buf + (c << 9) + lane * 8);
      gld_lds16(Bg + (size_t)row * ldb + kt + scol, buf + 8192 + (c << 9) + lane * 8);
    }
  };

  const int NT = K >> 5;
  // prologue: stage t=0,1,2 into bufs 0,1,2 -> 12 loads in flight; wait t=0 (vmcnt 8)
  stage(sm, 0);
  stage(sm + 16384, 32);
  stage(sm + 32768, 64);
  VMW8();
  SB();

  for (int tb = 0; tb < NT; tb += 4) {
#pragma unroll
    for (int u = 0; u < 4; ++u) {
      const int t = tb + u;
      const bf16_t* ab = sm + u * 16384;
      const bf16_t* bb = ab + 8192;
      if (t + 3 < NT) stage(sm + ((u + 3) & 3) * 16384, (t + 3) << 5);

      bf16x8 aF[8], bF[4];
#pragma unroll
      for (int jj = 0; jj < 4; ++jj)
        bF[jj] = *(const bf16x8*)&bb[(jj * 64 + wn * 16 + lr) * 32 + lg * 8];
#pragma unroll
      for (int ii = 0; ii < 8; ++ii)
        aF[ii] = *(const bf16x8*)&ab[((((ii >> 2) << 7) + ((ii & 3) << 5) + (wm << 4)) + lr) * 32 + lg * 8];

      __builtin_amdgcn_s_setprio(1);
#pragma unroll
      for (int ii = 0; ii < 8; ++ii)
#pragma unroll
        for (int jj = 0; jj < 4; ++jj)
          acc[ii][jj] = __builtin_amdgcn_mfma_f32_16x16x32_bf16(aF[ii], bF[jj], acc[ii][jj], 0, 0, 0);
      __builtin_amdgcn_s_setprio(0);

      SCHED();                      // keep this stage's ops above the barrier
      if (t + 3 < NT)      { VMW8(); SB(); }   // t+1 landed; t+2,t+3 in flight
      else if (t == NT - 3) { VMW4(); SB(); }  // tail: t+1 landed; t+2 in flight
      else if (t == NT - 2) { VMW0(); SB(); }  // tail: last buffer landed
      SCHED();
    }
  }

  // ---- epilogue ----
#pragma unroll
  for (int i = 0; i < 8; ++i) {
    const int mr = ((i >> 2) << 7) + ((i & 3) << 5) + (wm << 4);
#pragma unroll
    for (int j = 0; j < 4; ++j) {
      const int nc = j * 64 + (wn << 4);
#pragma unroll
      for (int r = 0; r < 4; ++r) {
        int row = m0 + mr + lg * 4 + r;
        int col = n0 + nc + lr;
        float v = acc[i][j][r] * scale;
        if constexpr (EPI == EPI_BF16_BIAS || EPI == EPI_F32_BIAS_RES || EPI == EPI_BF16_BIAS_GELU)
          v += bias[col];
        if constexpr (EPI == EPI_BF16_BIAS_GELU)
          v = gelu_exact(v);
        if constexpr (EPI == EPI_F32_BIAS_RES)
          v += resid[(size_t)row * ldc + col];
        if constexpr (EPI == EPI_BF16_BIAS || EPI == EPI_BF16 || EPI == EPI_BF16_BIAS_GELU) {
          ((bf16_t*)Cp)[(size_t)z * strideC + (size_t)row * ldc + col] = (bf16_t)v;
        } else {
          ((float*)Cp)[(size_t)z * strideC + (size_t)row * ldc + col] = v;
        }
      }
    }
  }
}

// ---------------- combine: out = x2 + p0 + p1 + bias (f32, H=2048 cols) ----------------
__global__ __launch_bounds__(256) void tb_combine(
    const float* __restrict__ x2, const float* __restrict__ p0,
    const float* __restrict__ p1, const float* __restrict__ bias,
    float* __restrict__ out)
{
  size_t o = ((size_t)blockIdx.x * 256 + threadIdx.x) * 4;
  float4 a = *(const float4*)(x2 + o);
  float4 b = *(const float4*)(p0 + o);
  float4 c = *(const float4*)(p1 + o);
  float4 bb = *(const float4*)(bias + (o & 2047));
  float4 r;
  r.x = a.x + b.x + c.x + bb.x;
  r.y = a.y + b.y + c.y + bb.y;
  r.z = a.z + b.z + c.z + bb.z;
  r.w = a.w + b.w + c.w + bb.w;
  *(float4*)(out + o) = r;
}

// ---------------- transpose + cast f32[R][C] -> bf16[C][R] ----------------
__global__ __launch_bounds__(256) void tb_transpose_cast(
    const float* __restrict__ in, bf16_t* __restrict__ outT, int R, int C)
{
  __shared__ float tile[32][33];
  int c0 = blockIdx.x * 32;
  int r0 = blockIdx.y * 32;
  int t = threadIdx.x;
  int r = t >> 3;
  int c4 = (t & 7) * 4;
  float4 d = *(const float4*)(in + (size_t)(r0 + r) * C + c0 + c4);
  tile[r][c4 + 0] = d.x; tile[r][c4 + 1] = d.y; tile[r][c4 + 2] = d.z; tile[r][c4 + 3] = d.w;
  __syncthreads();
  int c = t >> 3;
  int r4 = (t & 7) * 4;
  bf16x4 o;
  o[0] = (bf16_t)tile[r4 + 0][c];
  o[1] = (bf16_t)tile[r4 + 1][c];
  o[2] = (bf16_t)tile[r4 + 2][c];
  o[3] = (bf16_t)tile[r4 + 3][c];
  *(bf16x4*)(outT + (size_t)(c0 + c) * R + r0 + r4) = o;
}

// ---------------- transpose bf16 [R][C](ldin) -> bf16 [C][R](ldout), batched ----------------
__global__ __launch_bounds__(256) void tb_transpose_bf16(
    const bf16_t* __restrict__ in, int ldin, long long sIn,
    bf16_t* __restrict__ out, int ldout, long long sOut)
{
  __shared__ bf16_t tile[32][40];
  int z = blockIdx.z;
  const bf16_t* src = in + (size_t)z * sIn;
  bf16_t* dst = out + (size_t)z * sOut;
  int c0 = blockIdx.x * 32;
  int r0 = blockIdx.y * 32;
  int t = threadIdx.x;
  int r = t >> 3;
  int c4 = (t & 7) * 4;
  bf16x4 d = *(const bf16x4*)(src + (size_t)(r0 + r) * ldin + c0 + c4);
  *(bf16x4*)&tile[r][c4] = d;
  __syncthreads();
  int c = t >> 3;
  int r4 = (t & 7) * 4;
  bf16x4 o;
  o[0] = tile[r4 + 0][c];
  o[1] = tile[r4 + 1][c];
  o[2] = tile[r4 + 2][c];
  o[3] = tile[r4 + 3][c];
  *(bf16x4*)(dst + (size_t)(c0 + c) * ldout + r0 + r4) = o;
}

// ---------------- LayerNorm (fp32 in, bf16 out), one block per row of 2048 ----------------
__global__ __launch_bounds__(256) void tb_layernorm(
    const float* __restrict__ x, const float* __restrict__ g, const float* __restrict__ b,
    bf16_t* __restrict__ h)
{
  __shared__ float sa[4], sb[4];
  int row = blockIdx.x;
  int t = threadIdx.x;
  const float* xr = x + (size_t)row * 2048;
  float4 v0 = *(const float4*)(xr + t * 8);
  float4 v1 = *(const float4*)(xr + t * 8 + 4);
  float a[8] = {v0.x, v0.y, v0.z, v0.w, v1.x, v1.y, v1.z, v1.w};
  float s = 0.f, q = 0.f;
#pragma unroll
  for (int j = 0; j < 8; ++j) { s += a[j]; q += a[j] * a[j]; }
#pragma unroll
  for (int o = 32; o; o >>= 1) { s += __shfl_down(s, o); q += __shfl_down(q, o); }
  int w = t >> 6, l = t & 63;
  if (l == 0) { sa[w] = s; sb[w] = q; }
  __syncthreads();
  if (t == 0) {
    sa[0] = sa[0] + sa[1] + sa[2] + sa[3];
    sb[0] = sb[0] + sb[1] + sb[2] + sb[3];
  }
  __syncthreads();
  float mu = sa[0] * (1.0f / 2048.0f);
  float var = sb[0] * (1.0f / 2048.0f) - mu * mu;
  float rs = rsqrtf(var + 1e-5f);
  float4 g0 = *(const float4*)(g + t * 8);
  float4 g1 = *(const float4*)(g + t * 8 + 4);
  float4 b0 = *(const float4*)(b + t * 8);
  float4 b1 = *(const float4*)(b + t * 8 + 4);
  float gv[8] = {g0.x, g0.y, g0.z, g0.w, g1.x, g1.y, g1.z, g1.w};
  float bv[8] = {b0.x, b0.y, b0.z, b0.w, b1.x, b1.y, b1.z, b1.w};
  bf16x8 o8;
#pragma unroll
  for (int j = 0; j < 8; ++j) o8[j] = (bf16_t)((a[j] - mu) * rs * gv[j] + bv[j]);
  *(bf16x8*)(h + (size_t)row * 2048 + t * 8) = o8;
}

// ---------------- Softmax (fp32 in, bf16 out), one block per row of 2048 ----------------
__global__ __launch_bounds__(256) void tb_softmax(
    const float* __restrict__ S, bf16_t* __restrict__ P)
{
  __shared__ float sa[4];
  int row = blockIdx.x;
  int t = threadIdx.x;
  const float* sr = S + (size_t)row * 2048;
  float4 a0 = *(const float4*)(sr + t * 8);
  float4 a1 = *(const float4*)(sr + t * 8 + 4);
  float v[8] = {a0.x, a0.y, a0.z, a0.w, a1.x, a1.y, a1.z, a1.w};
  float m = v[0];
#pragma unroll
  for (int j = 1; j < 8; ++j) m = fmaxf(m, v[j]);
#pragma unroll
  for (int o = 32; o; o >>= 1) m = fmaxf(m, __shfl_down(m, o));
  int w = t >> 6, l = t & 63;
  if (l == 0) sa[w] = m;
  __syncthreads();
  if (t == 0) sa[0] = fmaxf(fmaxf(sa[0], sa[1]), fmaxf(sa[2], sa[3]));
  __syncthreads();
  m = sa[0];
  __syncthreads();
  float s = 0.f;
#pragma unroll
  for (int j = 0; j < 8; ++j) { v[j] = expf(v[j] - m); s += v[j]; }
#pragma unroll
  for (int o = 32; o; o >>= 1) s += __shfl_down(s, o);
  if (l == 0) sa[w] = s;
  __syncthreads();
  if (t == 0) sa[0] = sa[0] + sa[1] + sa[2] + sa[3];
  __syncthreads();
  float inv = 1.0f / sa[0];
  bf16x8 o8;
#pragma unroll
  for (int j = 0; j < 8; ++j) o8[j] = (bf16_t)(v[j] * inv);
  *(bf16x8*)(P + (size_t)row * 2048 + t * 8) = o8;
}

// ---------------- host ----------------
extern "C" void kernel_launch(void* const* d_in, const int* in_sizes, int n_in,
                              void* d_out, int out_size, void* d_ws, size_t ws_size,
                              hipStream_t stream) {
  const float* x     = (const float*)d_in[0];
  const float* ln1_g = (const float*)d_in[1];
  const float* ln1_b = (const float*)d_in[2];
  const float* ln2_g = (const float*)d_in[3];
  const float* ln2_b = (const float*)d_in[4];
  const float* qkv_w = (const float*)d_in[5];
  const float* qkv_b = (const float*)d_in[6];
  const float* out_w = (const float*)d_in[7];
  const float* out_b = (const float*)d_in[8];
  const float* w1    = (const float*)d_in[9];
  const float* b1    = (const float*)d_in[10];
  const float* w2    = (const float*)d_in[11];
  const float* b2    = (const float*)d_in[12];
  float* out = (float*)d_out;
  char* ws = (char*)d_ws;

  // workspace layout (bytes), total 268,435,456
  bf16_t* qkv_wT = (bf16_t*)(ws + 0);           // [6144][2048] bf16 = 25,165,824
  bf16_t* out_wT = (bf16_t*)(ws + 25165824);    // [2048][2048] bf16 =  8,388,608
  bf16_t* w1T    = (bf16_t*)(ws + 33554432);    // [8192][2048] bf16 = 33,554,432
  bf16_t* w2T    = (bf16_t*)(ws + 67108864);    // [2048][8192] bf16 = 33,554,432
  bf16_t* h_bf   = (bf16_t*)(ws + 100663296);   // [4096][2048] bf16 = 16,777,216
  bf16_t* qkv_bf = (bf16_t*)(ws + 117440512);   // [4096][6144] bf16 = 50,331,648
  float*  scores = (float*)(ws + 167772160);    // [2][2048][2048] f32 = 33,554,432
  bf16_t* attn_bf= (bf16_t*)(ws + 201326592);   // [2][2048][2048] bf16 = 16,777,216
  bf16_t* ao_bf  = (bf16_t*)(ws + 218103808);   // [4096][2048] bf16 = 16,777,216
  float*  x2     = (float*)(ws + 234881024);    // [4096][2048] f32 = 33,554,432
  bf16_t* mid_bf = (bf16_t*)(ws + 117440512);   // alias qkv_bf+scores (dead by MLP1)
  bf16_t* Vt     = (bf16_t*)(ws + 234881024);   // aliases x2 (dead by step 8)
  float*  part0  = (float*)(ws + 0);            // [4096][2048] f32, aliases weights (dead by MLP2)
  float*  part1  = (float*)(ws + 201326592);    // [4096][2048] f32, aliases attn_bf+ao_bf (dead by MLP2)

  const float inv_sqrt_h = 0.022097086912079608f; // 1/sqrt(2048)

  // 1) weight transposes (fp32 -> bf16 [N][K])
  tb_transpose_cast<<<dim3(6144 / 32, 2048 / 32), 256, 0, stream>>>(qkv_w, qkv_wT, 2048, 6144);
  tb_transpose_cast<<<dim3(2048 / 32, 2048 / 32), 256, 0, stream>>>(out_w, out_wT, 2048, 2048);
  tb_transpose_cast<<<dim3(8192 / 32, 2048 / 32), 256, 0, stream>>>(w1, w1T, 2048, 8192);
  tb_transpose_cast<<<dim3(2048 / 32, 8192 / 32), 256, 0, stream>>>(w2, w2T, 8192, 2048);

  // 2) LN1: x -> h_bf
  tb_layernorm<<<4096, 256, 0, stream>>>(x, ln1_g, ln1_b, h_bf);

  // 3) QKV: h_bf @ qkv_w + qkv_b -> qkv_bf  (M=4096, N=6144, K=2048)
  tb_gemm8<EPI_BF16_BIAS><<<dim3(24, 16, 1), 512, 0, stream>>>(
      h_bf, 2048, 0, qkv_wT, 2048, 0, qkv_b, nullptr, qkv_bf, 6144, 0, 2048, 1.0f);

  // 4) V transpose: qkv_bf[z][t][4096+h] -> Vt[z][h][t]
  tb_transpose_bf16<<<dim3(64, 64, 2), 256, 0, stream>>>(
      qkv_bf + 4096, 6144, 2048LL * 6144, Vt, 2048, 2048LL * 2048);

  // 5) scores[z] = q[z] @ k[z]^T / sqrt(H)  (M=N=K=2048, z=2)
  tb_gemm8<EPI_F32_SCALE><<<dim3(8, 8, 2), 512, 0, stream>>>(
      qkv_bf, 6144, 2048LL * 6144, qkv_bf + 2048, 6144, 2048LL * 6144,
      nullptr, nullptr, scores, 2048, 2048LL * 2048, 2048, inv_sqrt_h);

  // 6) softmax rows -> attn_bf
  tb_softmax<<<4096, 256, 0, stream>>>(scores, attn_bf);

  // 7) PV: attn[z] @ v[z] -> ao_bf ; B = Vt[z] is [N=h][K=t]
  tb_gemm8<EPI_BF16><<<dim3(8, 8, 2), 512, 0, stream>>>(
      attn_bf, 2048, 2048LL * 2048, Vt, 2048, 2048LL * 2048,
      nullptr, nullptr, ao_bf, 2048, 2048LL * 2048, 2048, 1.0f);

  // 8) out-proj + residual: x2 = x + ao_bf @ out_w + out_b  (M=4096, N=2048, K=2048)
  tb_gemm8<EPI_F32_BIAS_RES><<<dim3(8, 16, 1), 512, 0, stream>>>(
      ao_bf, 2048, 0, out_wT, 2048, 0, out_b, x, x2, 2048, 0, 2048, 1.0f);

  // 9) LN2: x2 -> h_bf (reuse)
  tb_layernorm<<<4096, 256, 0, stream>>>(x2, ln2_g, ln2_b, h_bf);

  // 10) MLP1 + GELU: mid_bf = gelu(h_bf @ w1 + b1)  (M=4096, N=8192, K=2048)
  tb_gemm8<EPI_BF16_BIAS_GELU><<<dim3(32, 16, 1), 512, 0, stream>>>(
      h_bf, 2048, 0, w1T, 2048, 0, b1, nullptr, mid_bf, 8192, 0, 2048, 1.0f);

  // 11) MLP2 split-K x2: part_z = mid_bf[:, z*4096:] @ w2T[:, z*4096:]^T  (256 blocks)
  tb_gemm8<EPI_F32_SCALE><<<dim3(8, 16, 2), 512, 0, stream>>>(
      mid_bf, 8192, 4096, w2T, 8192, 4096,
      nullptr, nullptr, part0, 2048, 50331648LL, 4096, 1.0f);

  // 12) combine: out = x2 + part0 + part1 + b2
  tb_combine<<<8192, 256, 0, stream>>>(x2, part0, part1, b2, out);
}

// Round 7
// 793.293 us; speedup vs baseline: 1.0952x; 1.0952x over previous
//
#include <hip/hip_runtime.h>
#include <hip/hip_bf16.h>
#include <math.h>

typedef __bf16 bf16_t;
typedef __bf16 bf16x8 __attribute__((ext_vector_type(8)));
typedef __bf16 bf16x4 __attribute__((ext_vector_type(4)));
typedef float  f32x4  __attribute__((ext_vector_type(4)));

enum { EPI_BF16_BIAS = 0, EPI_F32_SCALE = 1, EPI_BF16 = 2, EPI_F32_BIAS_RES = 3, EPI_BF16_BIAS_GELU = 4 };

__device__ __forceinline__ float gelu_exact(float v) {
  return 0.5f * v * (1.0f + erff(v * 0.7071067811865476f));
}

__device__ __forceinline__ void gld_lds16(const bf16_t* g, bf16_t* l) {
  __builtin_amdgcn_global_load_lds(
      (const __attribute__((address_space(1))) uint32_t*)(uintptr_t)g,
      (__attribute__((address_space(3))) uint32_t*)(uintptr_t)l, 16, 0, 0);
}

#define SB()    __builtin_amdgcn_s_barrier()
#define LGKM0() do { asm volatile("s_waitcnt lgkmcnt(0)" ::: "memory"); __builtin_amdgcn_sched_barrier(0); } while(0)
#define VMW(N)  asm volatile("s_waitcnt vmcnt(" #N ")" ::: "memory")

#define MFMA16(BASE) do { \
  __builtin_amdgcn_s_setprio(1); \
  _Pragma("unroll") for (int ii = 0; ii < 4; ++ii) \
  _Pragma("unroll") for (int jj = 0; jj < 4; ++jj) \
    acc[(BASE)+ii][jj] = __builtin_amdgcn_mfma_f32_16x16x32_bf16(aF[ii], bF[jj], acc[(BASE)+ii][jj], 0, 0, 0); \
  __builtin_amdgcn_s_setprio(0); } while(0)

// ---------------- GEMM: 256x256 tile, BK=64, 8 waves, m201 8-phase pipeline ----
// C[M][N] = A[M][K] @ B^T (+ epilogue). A:[M][K] bf16 (lda), B:[N][K] bf16 (ldb).
// M,N multiples of 256; K multiple of 128 (NT even, >=4).
// LDS: 2 buffers x 4 regions (A-ks0, A-ks1, B-ks0, B-ks1), each 256 rows x 32 elems
// (16 KB). Per K-tile: 4 phases, each = { 4-8 swizzled ds_read_b128 ; stage ONE
// half-tile for t+2 (2 gload_lds) ; barrier ; lgkm0 ; 16 MFMA ; barrier }.
// vmcnt(6) once per K-tile at ph3 (confirms tile t+1 fully landed; 3 half-tiles of
// t+2 stay in flight). Read swizzle: slot = (lg + (lr>>1)) & 3 -> 2 lanes/bank-quad
// (free); staging pre-applies the inverse permutation on the global source column.
template<int EPI>
__global__ __launch_bounds__(512, 2) void tb_gemm8(
    const bf16_t* __restrict__ A, int lda, long long strideA,
    const bf16_t* __restrict__ B, int ldb, long long strideB,
    const float* __restrict__ bias,
    const float* __restrict__ resid,
    void* __restrict__ Cp, int ldc, long long strideC,
    int K, float scale)
{
  __shared__ __align__(16) bf16_t sm[65536];  // 128 KiB

  const int tid = threadIdx.x;
  const int lane = tid & 63;
  const int wid = tid >> 6;
  const int wm = wid >> 2;   // 0..1
  const int wn = wid & 3;    // 0..3
  const int lr = lane & 15;
  const int lg = lane >> 4;
  const int z = blockIdx.z;
  const int m0 = blockIdx.y * 256;
  const int n0 = blockIdx.x * 256;

  const bf16_t* Ag = A + (size_t)z * strideA + (size_t)m0 * lda;
  const bf16_t* Bg = B + (size_t)z * strideB + (size_t)n0 * ldb;

  // staging geometry: each call covers one 16KB region (256 rows x 32 elems);
  // thread stages rows sr0 and sr0+16, 16B each, source column pre-permuted.
  const int sr0 = (wid << 5) + (lane >> 2);
  const int sl  = ((((lane & 3) - (lane >> 3)) & 3) << 3);
  const int sdst = (wid << 10) + lane * 8;

  // read geometry: frag at (row = rowbase + lr, slot = (lg + (lr>>1)) & 3)
  const int rdo = lr * 32 + (((lg + (lr >> 1)) & 3) << 3);
  const int wmo = wm * 512;   // wm*16 rows * 32
  const int wno = wn * 512;

  f32x4 acc[8][4];
#pragma unroll
  for (int i = 0; i < 8; ++i)
#pragma unroll
    for (int j = 0; j < 4; ++j) acc[i][j] = (f32x4){0.f, 0.f, 0.f, 0.f};

  auto stageA = [&](bf16_t* region, int kc) {
    gld_lds16(Ag + (size_t)sr0 * lda + kc + sl, region + sdst);
    gld_lds16(Ag + (size_t)(sr0 + 16) * lda + kc + sl, region + sdst + 512);
  };
  auto stageB = [&](bf16_t* region, int kc) {
    gld_lds16(Bg + (size_t)sr0 * ldb + kc + sl, region + sdst);
    gld_lds16(Bg + (size_t)(sr0 + 16) * ldb + kc + sl, region + sdst + 512);
  };

  const int NT = K >> 6;
  // region offsets (elems): AKS0=0, AKS1=8192, BKS0=16384, BKS1=24576; bufs at 0/32768.
  // prologue: tile0 (4 half-tiles) + tile1's first 3, in steady-state order.
  stageA(sm + 0, 0);
  stageB(sm + 16384, 0);
  stageA(sm + 8192, 32);
  stageB(sm + 24576, 32);
  stageB(sm + 32768 + 16384, 64);   // B-ks0(1)
  stageA(sm + 32768 + 0, 64);       // A-ks0(1)
  stageB(sm + 32768 + 24576, 96);   // B-ks1(1)
  VMW(6);                            // tile 0 fully landed; tile 1's 3 in flight
  SB();

  bf16x8 aF[4], bF[4];

  auto tile = [&](int t, bf16_t* cur, bf16_t* oth) {
    // ---- ph0: (mh0, ks0) ----
#pragma unroll
    for (int jj = 0; jj < 4; ++jj) bF[jj] = *(const bf16x8*)(cur + 16384 + jj * 2048 + wno + rdo);
#pragma unroll
    for (int ii = 0; ii < 4; ++ii) aF[ii] = *(const bf16x8*)(cur + 0 + ii * 1024 + wmo + rdo);
    if (t + 1 < NT) stageA(oth + 8192, ((t + 1) << 6) + 32);   // A-ks1(t+1)
    SB(); LGKM0();
    MFMA16(0);
    SB();
    // ---- ph1: (mh1, ks0) ----
#pragma unroll
    for (int ii = 0; ii < 4; ++ii) aF[ii] = *(const bf16x8*)(cur + 4096 + ii * 1024 + wmo + rdo);
    if (t + 2 < NT) stageB(cur + 16384, (t + 2) << 6);         // B-ks0(t+2)
    SB(); LGKM0();
    MFMA16(4);
    SB();
    // ---- ph2: (mh0, ks1) ----
#pragma unroll
    for (int jj = 0; jj < 4; ++jj) bF[jj] = *(const bf16x8*)(cur + 24576 + jj * 2048 + wno + rdo);
#pragma unroll
    for (int ii = 0; ii < 4; ++ii) aF[ii] = *(const bf16x8*)(cur + 8192 + ii * 1024 + wmo + rdo);
    if (t + 2 < NT) stageA(cur + 0, (t + 2) << 6);             // A-ks0(t+2)
    SB(); LGKM0();
    MFMA16(0);
    SB();
    // ---- ph3: (mh1, ks1) ----
#pragma unroll
    for (int ii = 0; ii < 4; ++ii) aF[ii] = *(const bf16x8*)(cur + 12288 + ii * 1024 + wmo + rdo);
    if (t + 2 < NT) { stageB(cur + 24576, ((t + 2) << 6) + 32); VMW(6); }  // B-ks1(t+2); t+1 landed
    else if (t + 1 < NT) { VMW(0); }                                       // tail: drain for last tile
    SB(); LGKM0();
    MFMA16(4);
    SB();
  };

  for (int t = 0; t < NT; t += 2) {
    tile(t, sm, sm + 32768);
    tile(t + 1, sm + 32768, sm);
  }

  // ---- epilogue ----
#pragma unroll
  for (int i = 0; i < 8; ++i) {
    const int mr = ((i >> 2) << 7) + ((i & 3) << 5) + (wm << 4);
#pragma unroll
    for (int j = 0; j < 4; ++j) {
      const int nc = j * 64 + (wn << 4);
#pragma unroll
      for (int r = 0; r < 4; ++r) {
        int row = m0 + mr + lg * 4 + r;
        int col = n0 + nc + lr;
        float v = acc[i][j][r] * scale;
        if constexpr (EPI == EPI_BF16_BIAS || EPI == EPI_F32_BIAS_RES || EPI == EPI_BF16_BIAS_GELU)
          v += bias[col];
        if constexpr (EPI == EPI_BF16_BIAS_GELU)
          v = gelu_exact(v);
        if constexpr (EPI == EPI_F32_BIAS_RES)
          v += resid[(size_t)row * ldc + col];
        if constexpr (EPI == EPI_BF16_BIAS || EPI == EPI_BF16 || EPI == EPI_BF16_BIAS_GELU) {
          ((bf16_t*)Cp)[(size_t)z * strideC + (size_t)row * ldc + col] = (bf16_t)v;
        } else {
          ((float*)Cp)[(size_t)z * strideC + (size_t)row * ldc + col] = v;
        }
      }
    }
  }
}

// ---------------- combine: out = x2 + p0 + p1 + bias (f32, H=2048 cols) ----------------
__global__ __launch_bounds__(256) void tb_combine(
    const float* __restrict__ x2, const float* __restrict__ p0,
    const float* __restrict__ p1, const float* __restrict__ bias,
    float* __restrict__ out)
{
  size_t o = ((size_t)blockIdx.x * 256 + threadIdx.x) * 4;
  float4 a = *(const float4*)(x2 + o);
  float4 b = *(const float4*)(p0 + o);
  float4 c = *(const float4*)(p1 + o);
  float4 bb = *(const float4*)(bias + (o & 2047));
  float4 r;
  r.x = a.x + b.x + c.x + bb.x;
  r.y = a.y + b.y + c.y + bb.y;
  r.z = a.z + b.z + c.z + bb.z;
  r.w = a.w + b.w + c.w + bb.w;
  *(float4*)(out + o) = r;
}

// ---------------- transpose + cast f32[R][C] -> bf16[C][R] ----------------
__global__ __launch_bounds__(256) void tb_transpose_cast(
    const float* __restrict__ in, bf16_t* __restrict__ outT, int R, int C)
{
  __shared__ float tile[32][33];
  int c0 = blockIdx.x * 32;
  int r0 = blockIdx.y * 32;
  int t = threadIdx.x;
  int r = t >> 3;
  int c4 = (t & 7) * 4;
  float4 d = *(const float4*)(in + (size_t)(r0 + r) * C + c0 + c4);
  tile[r][c4 + 0] = d.x; tile[r][c4 + 1] = d.y; tile[r][c4 + 2] = d.z; tile[r][c4 + 3] = d.w;
  __syncthreads();
  int c = t >> 3;
  int r4 = (t & 7) * 4;
  bf16x4 o;
  o[0] = (bf16_t)tile[r4 + 0][c];
  o[1] = (bf16_t)tile[r4 + 1][c];
  o[2] = (bf16_t)tile[r4 + 2][c];
  o[3] = (bf16_t)tile[r4 + 3][c];
  *(bf16x4*)(outT + (size_t)(c0 + c) * R + r0 + r4) = o;
}

// ---------------- transpose bf16 [R][C](ldin) -> bf16 [C][R](ldout), batched ----------------
__global__ __launch_bounds__(256) void tb_transpose_bf16(
    const bf16_t* __restrict__ in, int ldin, long long sIn,
    bf16_t* __restrict__ out, int ldout, long long sOut)
{
  __shared__ bf16_t tile[32][40];
  int z = blockIdx.z;
  const bf16_t* src = in + (size_t)z * sIn;
  bf16_t* dst = out + (size_t)z * sOut;
  int c0 = blockIdx.x * 32;
  int r0 = blockIdx.y * 32;
  int t = threadIdx.x;
  int r = t >> 3;
  int c4 = (t & 7) * 4;
  bf16x4 d = *(const bf16x4*)(src + (size_t)(r0 + r) * ldin + c0 + c4);
  *(bf16x4*)&tile[r][c4] = d;
  __syncthreads();
  int c = t >> 3;
  int r4 = (t & 7) * 4;
  bf16x4 o;
  o[0] = tile[r4 + 0][c];
  o[1] = tile[r4 + 1][c];
  o[2] = tile[r4 + 2][c];
  o[3] = tile[r4 + 3][c];
  *(bf16x4*)(dst + (size_t)(c0 + c) * ldout + r0 + r4) = o;
}

// ---------------- LayerNorm (fp32 in, bf16 out), one block per row of 2048 ----------------
__global__ __launch_bounds__(256) void tb_layernorm(
    const float* __restrict__ x, const float* __restrict__ g, const float* __restrict__ b,
    bf16_t* __restrict__ h)
{
  __shared__ float sa[4], sb[4];
  int row = blockIdx.x;
  int t = threadIdx.x;
  const float* xr = x + (size_t)row * 2048;
  float4 v0 = *(const float4*)(xr + t * 8);
  float4 v1 = *(const float4*)(xr + t * 8 + 4);
  float a[8] = {v0.x, v0.y, v0.z, v0.w, v1.x, v1.y, v1.z, v1.w};
  float s = 0.f, q = 0.f;
#pragma unroll
  for (int j = 0; j < 8; ++j) { s += a[j]; q += a[j] * a[j]; }
#pragma unroll
  for (int o = 32; o; o >>= 1) { s += __shfl_down(s, o); q += __shfl_down(q, o); }
  int w = t >> 6, l = t & 63;
  if (l == 0) { sa[w] = s; sb[w] = q; }
  __syncthreads();
  if (t == 0) {
    sa[0] = sa[0] + sa[1] + sa[2] + sa[3];
    sb[0] = sb[0] + sb[1] + sb[2] + sb[3];
  }
  __syncthreads();
  float mu = sa[0] * (1.0f / 2048.0f);
  float var = sb[0] * (1.0f / 2048.0f) - mu * mu;
  float rs = rsqrtf(var + 1e-5f);
  float4 g0 = *(const float4*)(g + t * 8);
  float4 g1 = *(const float4*)(g + t * 8 + 4);
  float4 b0 = *(const float4*)(b + t * 8);
  float4 b1 = *(const float4*)(b + t * 8 + 4);
  float gv[8] = {g0.x, g0.y, g0.z, g0.w, g1.x, g1.y, g1.z, g1.w};
  float bv[8] = {b0.x, b0.y, b0.z, b0.w, b1.x, b1.y, b1.z, b1.w};
  bf16x8 o8;
#pragma unroll
  for (int j = 0; j < 8; ++j) o8[j] = (bf16_t)((a[j] - mu) * rs * gv[j] + bv[j]);
  *(bf16x8*)(h + (size_t)row * 2048 + t * 8) = o8;
}

// ---------------- Softmax (fp32 in, bf16 out), one block per row of 2048 ----------------
__global__ __launch_bounds__(256) void tb_softmax(
    const float* __restrict__ S, bf16_t* __restrict__ P)
{
  __shared__ float sa[4];
  int row = blockIdx.x;
  int t = threadIdx.x;
  const float* sr = S + (size_t)row * 2048;
  float4 a0 = *(const float4*)(sr + t * 8);
  float4 a1 = *(const float4*)(sr + t * 8 + 4);
  float v[8] = {a0.x, a0.y, a0.z, a0.w, a1.x, a1.y, a1.z, a1.w};
  float m = v[0];
#pragma unroll
  for (int j = 1; j < 8; ++j) m = fmaxf(m, v[j]);
#pragma unroll
  for (int o = 32; o; o >>= 1) m = fmaxf(m, __shfl_down(m, o));
  int w = t >> 6, l = t & 63;
  if (l == 0) sa[w] = m;
  __syncthreads();
  if (t == 0) sa[0] = fmaxf(fmaxf(sa[0], sa[1]), fmaxf(sa[2], sa[3]));
  __syncthreads();
  m = sa[0];
  __syncthreads();
  float s = 0.f;
#pragma unroll
  for (int j = 0; j < 8; ++j) { v[j] = expf(v[j] - m); s += v[j]; }
#pragma unroll
  for (int o = 32; o; o >>= 1) s += __shfl_down(s, o);
  if (l == 0) sa[w] = s;
  __syncthreads();
  if (t == 0) sa[0] = sa[0] + sa[1] + sa[2] + sa[3];
  __syncthreads();
  float inv = 1.0f / sa[0];
  bf16x8 o8;
#pragma unroll
  for (int j = 0; j < 8; ++j) o8[j] = (bf16_t)(v[j] * inv);
  *(bf16x8*)(P + (size_t)row * 2048 + t * 8) = o8;
}

// ---------------- host ----------------
extern "C" void kernel_launch(void* const* d_in, const int* in_sizes, int n_in,
                              void* d_out, int out_size, void* d_ws, size_t ws_size,
                              hipStream_t stream) {
  const float* x     = (const float*)d_in[0];
  const float* ln1_g = (const float*)d_in[1];
  const float* ln1_b = (const float*)d_in[2];
  const float* ln2_g = (const float*)d_in[3];
  const float* ln2_b = (const float*)d_in[4];
  const float* qkv_w = (const float*)d_in[5];
  const float* qkv_b = (const float*)d_in[6];
  const float* out_w = (const float*)d_in[7];
  const float* out_b = (const float*)d_in[8];
  const float* w1    = (const float*)d_in[9];
  const float* b1    = (const float*)d_in[10];
  const float* w2    = (const float*)d_in[11];
  const float* b2    = (const float*)d_in[12];
  float* out = (float*)d_out;
  char* ws = (char*)d_ws;

  // workspace layout (bytes), total 268,435,456
  bf16_t* qkv_wT = (bf16_t*)(ws + 0);           // [6144][2048] bf16 = 25,165,824
  bf16_t* out_wT = (bf16_t*)(ws + 25165824);    // [2048][2048] bf16 =  8,388,608
  bf16_t* w1T    = (bf16_t*)(ws + 33554432);    // [8192][2048] bf16 = 33,554,432
  bf16_t* w2T    = (bf16_t*)(ws + 67108864);    // [2048][8192] bf16 = 33,554,432
  bf16_t* h_bf   = (bf16_t*)(ws + 100663296);   // [4096][2048] bf16 = 16,777,216
  bf16_t* qkv_bf = (bf16_t*)(ws + 117440512);   // [4096][6144] bf16 = 50,331,648
  float*  scores = (float*)(ws + 167772160);    // [2][2048][2048] f32 = 33,554,432
  bf16_t* attn_bf= (bf16_t*)(ws + 201326592);   // [2][2048][2048] bf16 = 16,777,216
  bf16_t* ao_bf  = (bf16_t*)(ws + 218103808);   // [4096][2048] bf16 = 16,777,216
  float*  x2     = (float*)(ws + 234881024);    // [4096][2048] f32 = 33,554,432
  bf16_t* mid_bf = (bf16_t*)(ws + 117440512);   // alias qkv_bf+scores (dead by MLP1)
  bf16_t* Vt     = (bf16_t*)(ws + 234881024);   // aliases x2 (dead by step 8)
  float*  part0  = (float*)(ws + 0);            // [4096][2048] f32, aliases weights (dead by MLP2)
  float*  part1  = (float*)(ws + 201326592);    // [4096][2048] f32, aliases attn_bf+ao_bf (dead by MLP2)

  const float inv_sqrt_h = 0.022097086912079608f; // 1/sqrt(2048)

  // 1) weight transposes (fp32 -> bf16 [N][K])
  tb_transpose_cast<<<dim3(6144 / 32, 2048 / 32), 256, 0, stream>>>(qkv_w, qkv_wT, 2048, 6144);
  tb_transpose_cast<<<dim3(2048 / 32, 2048 / 32), 256, 0, stream>>>(out_w, out_wT, 2048, 2048);
  tb_transpose_cast<<<dim3(8192 / 32, 2048 / 32), 256, 0, stream>>>(w1, w1T, 2048, 8192);
  tb_transpose_cast<<<dim3(2048 / 32, 8192 / 32), 256, 0, stream>>>(w2, w2T, 8192, 2048);

  // 2) LN1: x -> h_bf
  tb_layernorm<<<4096, 256, 0, stream>>>(x, ln1_g, ln1_b, h_bf);

  // 3) QKV: h_bf @ qkv_w + qkv_b -> qkv_bf  (M=4096, N=6144, K=2048)
  tb_gemm8<EPI_BF16_BIAS><<<dim3(24, 16, 1), 512, 0, stream>>>(
      h_bf, 2048, 0, qkv_wT, 2048, 0, qkv_b, nullptr, qkv_bf, 6144, 0, 2048, 1.0f);

  // 4) V transpose: qkv_bf[z][t][4096+h] -> Vt[z][h][t]
  tb_transpose_bf16<<<dim3(64, 64, 2), 256, 0, stream>>>(
      qkv_bf + 4096, 6144, 2048LL * 6144, Vt, 2048, 2048LL * 2048);

  // 5) scores[z] = q[z] @ k[z]^T / sqrt(H)  (M=N=K=2048, z=2)
  tb_gemm8<EPI_F32_SCALE><<<dim3(8, 8, 2), 512, 0, stream>>>(
      qkv_bf, 6144, 2048LL * 6144, qkv_bf + 2048, 6144, 2048LL * 6144,
      nullptr, nullptr, scores, 2048, 2048LL * 2048, 2048, inv_sqrt_h);

  // 6) softmax rows -> attn_bf
  tb_softmax<<<4096, 256, 0, stream>>>(scores, attn_bf);

  // 7) PV: attn[z] @ v[z] -> ao_bf ; B = Vt[z] is [N=h][K=t]
  tb_gemm8<EPI_BF16><<<dim3(8, 8, 2), 512, 0, stream>>>(
      attn_bf, 2048, 2048LL * 2048, Vt, 2048, 2048LL * 2048,
      nullptr, nullptr, ao_bf, 2048, 2048LL * 2048, 2048, 1.0f);

  // 8) out-proj + residual: x2 = x + ao_bf @ out_w + out_b  (M=4096, N=2048, K=2048)
  tb_gemm8<EPI_F32_BIAS_RES><<<dim3(8, 16, 1), 512, 0, stream>>>(
      ao_bf, 2048, 0, out_wT, 2048, 0, out_b, x, x2, 2048, 0, 2048, 1.0f);

  // 9) LN2: x2 -> h_bf (reuse)
  tb_layernorm<<<4096, 256, 0, stream>>>(x2, ln2_g, ln2_b, h_bf);

  // 10) MLP1 + GELU: mid_bf = gelu(h_bf @ w1 + b1)  (M=4096, N=8192, K=2048)
  tb_gemm8<EPI_BF16_BIAS_GELU><<<dim3(32, 16, 1), 512, 0, stream>>>(
      h_bf, 2048, 0, w1T, 2048, 0, b1, nullptr, mid_bf, 8192, 0, 2048, 1.0f);

  // 11) MLP2 split-K x2: part_z = mid_bf[:, z*4096:] @ w2T[:, z*4096:]^T  (256 blocks)
  tb_gemm8<EPI_F32_SCALE><<<dim3(8, 16, 2), 512, 0, stream>>>(
      mid_bf, 8192, 4096, w2T, 8192, 4096,
      nullptr, nullptr, part0, 2048, 50331648LL, 4096, 1.0f);

  // 12) combine: out = x2 + part0 + part1 + b2
  tb_combine<<<8192, 256, 0, stream>>>(x2, part0, part1, b2, out);
}